// Round 1
// baseline (216.366 us; speedup 1.0000x reference)
//
#include <hip/hip_runtime.h>

#define EPSV 1e-8f
#define PW   34          // 32 + 2 halo (zero pad)
#define NPIX 1024
#define NA   5
#define NOUT 17
#define NZC  150

__global__ __launch_bounds__(1024) void vin_fused(
    const float* __restrict__ map_in, const float* __restrict__ b0,
    const int*   __restrict__ act_in, const float* __restrict__ obs_in,
    const int*   __restrict__ step_p, const int*   __restrict__ vik_p,
    const float* __restrict__ Tb_w,  const float* __restrict__ Tb_b,
    const float* __restrict__ Tv_w,  const float* __restrict__ Tv_b,
    const float* __restrict__ Z1_w,  const float* __restrict__ Z1_b,
    const float* __restrict__ Z2_w,  const float* __restrict__ Z2_b,
    const float* __restrict__ O1_w,  const float* __restrict__ O1_b,
    const float* __restrict__ O3_w,  const float* __restrict__ O3_b,
    const float* __restrict__ R1_w,  const float* __restrict__ R1_b,
    const float* __restrict__ R2_w,  const float* __restrict__ R2_b,
    const float* __restrict__ FL_w,  const float* __restrict__ FL_b,
    float* __restrict__ out, int B)
{
    __shared__ float map0[PW*PW], map1[PW*PW], v_lds[PW*PW], b_lds[PW*PW];
    __shared__ float zc_w[NOUT*9], zc_b[NOUT];
    __shared__ float h_lds[NOUT], u_lds[NOUT], w_lds[NOUT];
    __shared__ float partials[16][6], sums[6];

    const int tid  = threadIdx.x;
    const int blk  = blockIdx.x;
    const int y    = tid >> 5, x = tid & 31;
    const int pidx = (y + 1) * PW + (x + 1);
    const int lane = tid & 63, wvid = tid >> 6;

    // ---- init: zero-padded LDS tiles ----
    for (int i = tid; i < PW*PW; i += NPIX) {
        map0[i] = 0.f; map1[i] = 0.f; v_lds[i] = 0.f; b_lds[i] = 0.f;
    }
    __syncthreads();
    map0[pidx]  = map_in[blk*2*NPIX + tid];
    map1[pidx]  = map_in[blk*2*NPIX + NPIX + tid];
    b_lds[pidx] = b0[blk*NPIX + tid];

    // ---- collapse Z2(1x1) o Z1(3x3) into one 17-ch 3x3 conv (no relu between) ----
    if (tid < NOUT*9) {
        const int o = tid / 9, k = tid % 9;
        float s = 0.f;
        for (int c = 0; c < NZC; ++c) s += Z2_w[o*NZC + c] * Z1_w[c*9 + k];
        zc_w[tid] = s;
    } else if (tid < NOUT*9 + NOUT) {
        const int o = tid - NOUT*9;
        float s = Z2_b[o];
        for (int c = 0; c < NZC; ++c) s += Z2_w[o*NZC + c] * Z1_b[c];
        zc_b[o] = s;
    }
    __syncthreads();

    // ---- stencil neighborhood into registers ----
    float m0[9], m1[9];
    #pragma unroll
    for (int k = 0; k < 9; ++k) {
        const int off = (y + k/3)*PW + x + (k%3);
        m0[k] = map0[off]; m1[k] = map1[off];
    }

    // ---- R = conv1x1(relu(conv3x3(map))) ; weights via wave-uniform (scalar) loads ----
    float r[NA];
    #pragma unroll
    for (int a = 0; a < NA; ++a) r[a] = R2_b[a];
    for (int c = 0; c < NZC; ++c) {
        float s = R1_b[c];
        const float* w1 = R1_w + c*18;
        #pragma unroll
        for (int k = 0; k < 9; ++k) s += m0[k] * w1[k];
        #pragma unroll
        for (int k = 0; k < 9; ++k) s += m1[k] * w1[9 + k];
        s = fmaxf(s, 0.f);
        #pragma unroll
        for (int a = 0; a < NA; ++a) r[a] += R2_w[a*NZC + c] * s;
    }

    // ---- Z: sigmoid(collapsed conv), normalized over 17 channels ----
    float z[NOUT];
    float zs = 0.f;
    #pragma unroll
    for (int o = 0; o < NOUT; ++o) {
        float s = zc_b[o];
        #pragma unroll
        for (int k = 0; k < 9; ++k) s += m0[k] * zc_w[o*9 + k];
        const float zz = 1.f / (1.f + expf(-s));
        z[o] = zz; zs += zz;
    }
    const float zn = 1.f / (zs + EPSV);
    #pragma unroll
    for (int o = 0; o < NOUT; ++o) z[o] *= zn;

    // ---- value iteration: VI_k sweeps fully in LDS ----
    float q[NA];
    #pragma unroll
    for (int a = 0; a < NA; ++a) q[a] = 0.f;
    const int K = vik_p[0];
    for (int it = 0; it < K; ++it) {
        float n[9];
        #pragma unroll
        for (int k = 0; k < 9; ++k) n[k] = v_lds[(y + k/3)*PW + x + (k%3)];
        float vmax = -3.4e38f;
        #pragma unroll
        for (int a = 0; a < NA; ++a) {
            float s = Tv_b[a] + r[a];
            #pragma unroll
            for (int k = 0; k < 9; ++k) s += n[k] * Tv_w[a*9 + k];
            q[a] = s;
            vmax = fmaxf(vmax, s);
        }
        __syncthreads();
        v_lds[pidx] = vmax;
        __syncthreads();
    }

    // ---- belief-propagation timestep loop ----
    const int S = step_p[0];
    for (int t = 0; t < S; ++t) {
        // w = softmax(tanh(o@O1^T+b)@O3^T+b) -- tiny, lanes 0..16 of wave 0
        if (tid < NOUT) {
            const float* ob = obs_in + (blk*S + t)*4;
            float hh = O1_b[tid];
            #pragma unroll
            for (int k = 0; k < 4; ++k) hh += ob[k] * O1_w[tid*4 + k];
            h_lds[tid] = tanhf(hh);
        }
        __syncthreads();
        if (tid < NOUT) {
            float u = O3_b[tid];
            for (int j = 0; j < NOUT; ++j) u += h_lds[j] * O3_w[tid*NOUT + j];
            u_lds[tid] = u;
        }
        __syncthreads();
        if (tid < NOUT) {
            float mx = u_lds[0];
            for (int j = 1; j < NOUT; ++j) mx = fmaxf(mx, u_lds[j]);
            float sm = 0.f;
            for (int j = 0; j < NOUT; ++j) sm += expf(u_lds[j] - mx);
            w_lds[tid] = expf(u_lds[tid] - mx) / sm;
        }
        __syncthreads();

        // b_pa: only the act-selected channel of the Tb conv (one-hot select)
        const int a_t = act_in[blk*S + t];
        float bp = Tb_b[a_t];
        #pragma unroll
        for (int k = 0; k < 9; ++k)
            bp += b_lds[(y + k/3)*PW + x + (k%3)] * Tb_w[a_t*9 + k];

        float zo = 0.f;
        #pragma unroll
        for (int o = 0; o < NOUT; ++o) zo += z[o] * w_lds[o];
        const float bn = bp * zo;

        // fused 6-way reduction: sums[0..4] = sum q[a]*bn, sums[5] = sum bn
        float v6[6];
        v6[5] = bn;
        #pragma unroll
        for (int a = 0; a < NA; ++a) v6[a] = q[a] * bn;
        #pragma unroll
        for (int k = 0; k < 6; ++k) {
            float vv = v6[k];
            for (int off = 32; off > 0; off >>= 1) vv += __shfl_down(vv, off);
            v6[k] = vv;
        }
        if (lane == 0) {
            #pragma unroll
            for (int k = 0; k < 6; ++k) partials[wvid][k] = v6[k];
        }
        __syncthreads();
        if (tid < 6) {
            float s = 0.f;
            for (int w2 = 0; w2 < 16; ++w2) s += partials[w2][tid];
            sums[tid] = s;
        }
        __syncthreads();

        const float inv = 1.f / (sums[5] + EPSV);
        if (tid < NA) {
            float oj = FL_b[tid];
            #pragma unroll
            for (int a = 0; a < NA; ++a) oj += (sums[a] * inv) * FL_w[tid*NA + a];
            out[(t*B + blk)*NA + tid] = oj;
        }
        b_lds[pidx] = bn * inv;   // normalized belief for next step
        __syncthreads();
    }

    // ---- final belief output ----
    out[S*B*NA + blk*NPIX + tid] = b_lds[pidx];
}

extern "C" void kernel_launch(void* const* d_in, const int* in_sizes, int n_in,
                              void* d_out, int out_size, void* d_ws, size_t ws_size,
                              hipStream_t stream)
{
    const float* map_in = (const float*)d_in[0];
    const float* b0     = (const float*)d_in[1];
    const int*   act_in = (const int*)  d_in[2];
    const float* obs_in = (const float*)d_in[3];
    // d_in[4] = is_start (unused: reference uses b0 either way)
    const int*   step_p = (const int*)  d_in[5];
    const int*   vik_p  = (const int*)  d_in[6];
    const float* Tb_w = (const float*)d_in[7];
    const float* Tb_b = (const float*)d_in[8];
    const float* Tv_w = (const float*)d_in[9];
    const float* Tv_b = (const float*)d_in[10];
    const float* Z1_w = (const float*)d_in[11];
    const float* Z1_b = (const float*)d_in[12];
    const float* Z2_w = (const float*)d_in[13];
    const float* Z2_b = (const float*)d_in[14];
    const float* O1_w = (const float*)d_in[15];
    const float* O1_b = (const float*)d_in[16];
    const float* O3_w = (const float*)d_in[17];
    const float* O3_b = (const float*)d_in[18];
    const float* R1_w = (const float*)d_in[19];
    const float* R1_b = (const float*)d_in[20];
    const float* R2_w = (const float*)d_in[21];
    const float* R2_b = (const float*)d_in[22];
    const float* FL_w = (const float*)d_in[23];
    const float* FL_b = (const float*)d_in[24];

    const int B = in_sizes[1] / NPIX;   // b0 is (B,32,32)

    hipLaunchKernelGGL(vin_fused, dim3(B), dim3(1024), 0, stream,
        map_in, b0, act_in, obs_in, step_p, vik_p,
        Tb_w, Tb_b, Tv_w, Tv_b, Z1_w, Z1_b, Z2_w, Z2_b,
        O1_w, O1_b, O3_w, O3_b, R1_w, R1_b, R2_w, R2_b,
        FL_w, FL_b, (float*)d_out, B);
}

// Round 5
// 187.936 us; speedup vs baseline: 1.1513x; 1.1513x over previous
//
#include <hip/hip_runtime.h>

#define EPSV 1e-8f
#define PW   34          // 32 + 2 halo (zero pad)
#define NPIX 1024
#define NA   5
#define NOUT 17
#define NZC  150
#define MAXS 8           // max supported step_size (harness uses 4)

// block=1024 (1 image/block), 1 block/CU -> allow 128 VGPRs (4 waves/EU min).
__global__ __launch_bounds__(1024, 4) void vin_fused(
    const float* __restrict__ map_in, const float* __restrict__ b0,
    const int*   __restrict__ act_in, const float* __restrict__ obs_in,
    const int*   __restrict__ step_p, const int*   __restrict__ vik_p,
    const float* __restrict__ Tb_w,  const float* __restrict__ Tb_b,
    const float* __restrict__ Tv_w,  const float* __restrict__ Tv_b,
    const float* __restrict__ Z1_w,  const float* __restrict__ Z1_b,
    const float* __restrict__ Z2_w,  const float* __restrict__ Z2_b,
    const float* __restrict__ O1_w,  const float* __restrict__ O1_b,
    const float* __restrict__ O3_w,  const float* __restrict__ O3_b,
    const float* __restrict__ R1_w,  const float* __restrict__ R1_b,
    const float* __restrict__ R2_w,  const float* __restrict__ R2_b,
    const float* __restrict__ FL_w,  const float* __restrict__ FL_b,
    float* __restrict__ out, int B)
{
    __shared__ float map0[PW*PW], map1[PW*PW], v_lds[PW*PW], b_lds[PW*PW];
    __shared__ float zc_w[NOUT*9], zc_b[NOUT];
    __shared__ float h_all[MAXS][NOUT], u_all[MAXS][NOUT], w_all[MAXS][NOUT];
    __shared__ float zo_lds[MAXS * NPIX];      // per-pixel Z.w_t, frees z[17] regs
    __shared__ float partials[16][6], sums[6];

    const int tid  = threadIdx.x;
    const int blk  = blockIdx.x;
    const int y    = tid >> 5, x = tid & 31;
    const int pidx = (y + 1) * PW + (x + 1);
    const int lane = tid & 63, wvid = tid >> 6;

    const int S = step_p[0];
    const int K = vik_p[0];

    // ---- init: zero-padded LDS tiles ----
    for (int i = tid; i < PW*PW; i += NPIX) {
        map0[i] = 0.f; map1[i] = 0.f; v_lds[i] = 0.f; b_lds[i] = 0.f;
    }
    __syncthreads();
    map0[pidx]  = map_in[blk*2*NPIX + tid];
    map1[pidx]  = map_in[blk*2*NPIX + NPIX + tid];
    b_lds[pidx] = b0[blk*NPIX + tid];

    // ---- collapse Z2(1x1) o Z1(3x3) into one 17-ch 3x3 conv (no relu between) ----
    if (tid < NOUT*9) {
        const int o = tid / 9, k = tid % 9;
        float s = 0.f;
        for (int c = 0; c < NZC; ++c) s += Z2_w[o*NZC + c] * Z1_w[c*9 + k];
        zc_w[tid] = s;
    } else if (tid < NOUT*9 + NOUT) {
        const int o = tid - NOUT*9;
        float s = Z2_b[o];
        for (int c = 0; c < NZC; ++c) s += Z2_w[o*NZC + c] * Z1_b[c];
        zc_b[o] = s;
    }

    // ---- observation MLP for ALL timesteps upfront (threads 256..256+S*17) ----
    const int mt = tid - 256;             // (t,o) pair index
    const int mT = mt / NOUT, mO = mt % NOUT;
    if (mt >= 0 && mt < S*NOUT) {
        const float* ob = obs_in + (blk*S + mT)*4;
        float hh = O1_b[mO];
        #pragma unroll
        for (int k = 0; k < 4; ++k) hh += ob[k] * O1_w[mO*4 + k];
        h_all[mT][mO] = tanhf(hh);
    }
    __syncthreads();
    if (mt >= 0 && mt < S*NOUT) {
        float u = O3_b[mO];
        #pragma unroll
        for (int j = 0; j < NOUT; ++j) u += h_all[mT][j] * O3_w[mO*NOUT + j];
        u_all[mT][mO] = u;
    }
    __syncthreads();
    if (mt >= 0 && mt < S*NOUT) {
        float mx = u_all[mT][0];
        #pragma unroll
        for (int j = 1; j < NOUT; ++j) mx = fmaxf(mx, u_all[mT][j]);
        float sm = 0.f;
        #pragma unroll
        for (int j = 0; j < NOUT; ++j) sm += expf(u_all[mT][j] - mx);
        w_all[mT][mO] = expf(u_all[mT][mO] - mx) / sm;
    }
    __syncthreads();

    // ---- stencil neighborhood into registers ----
    float m0[9], m1[9];
    #pragma unroll
    for (int k = 0; k < 9; ++k) {
        const int off = (y + k/3)*PW + x + (k%3);
        m0[k] = map0[off]; m1[k] = map1[off];
    }

    // ---- R = conv1x1(relu(conv3x3(map))); weights wave-uniform -> s_load ----
    float r[NA];
    #pragma unroll
    for (int a = 0; a < NA; ++a) r[a] = R2_b[a];
    for (int c = 0; c < NZC; ++c) {
        float s = R1_b[c];
        const float* w1 = R1_w + c*18;
        #pragma unroll
        for (int k = 0; k < 9; ++k) s += m0[k] * w1[k];
        #pragma unroll
        for (int k = 0; k < 9; ++k) s += m1[k] * w1[9 + k];
        s = fmaxf(s, 0.f);
        #pragma unroll
        for (int a = 0; a < NA; ++a) r[a] += R2_w[a*NZC + c] * s;
    }

    // ---- Z: sigmoid(collapsed conv), normalize over 17 ch, then collapse
    //      immediately against w_t -> zo (so z[17] dies before the VI loop) ----
    {
        float z[NOUT];
        float zs = 0.f;
        #pragma unroll
        for (int o = 0; o < NOUT; ++o) {
            float s = zc_b[o];
            #pragma unroll
            for (int k = 0; k < 9; ++k) s += m0[k] * zc_w[o*9 + k];
            const float zz = 1.f / (1.f + expf(-s));
            z[o] = zz; zs += zz;
        }
        const float zn = 1.f / (zs + EPSV);
        for (int t = 0; t < S; ++t) {
            float zo = 0.f;
            #pragma unroll
            for (int o = 0; o < NOUT; ++o) zo += z[o] * w_all[t][o];
            zo_lds[t*NPIX + tid] = zo * zn;
        }
    }

    // ---- value iteration: K sweeps fully in LDS; live regs = r[5], q[5] ----
    float q[NA];
    #pragma unroll
    for (int a = 0; a < NA; ++a) q[a] = 0.f;
    for (int it = 0; it < K; ++it) {
        float n[9];
        #pragma unroll
        for (int k = 0; k < 9; ++k) n[k] = v_lds[(y + k/3)*PW + x + (k%3)];
        float vmax = -3.4e38f;
        #pragma unroll
        for (int a = 0; a < NA; ++a) {
            float s = Tv_b[a] + r[a];
            #pragma unroll
            for (int k = 0; k < 9; ++k) s += n[k] * Tv_w[a*9 + k];
            q[a] = s;
            vmax = fmaxf(vmax, s);
        }
        __syncthreads();
        v_lds[pidx] = vmax;
        __syncthreads();
    }

    // ---- belief-propagation timestep loop (w_t, zo precomputed) ----
    for (int t = 0; t < S; ++t) {
        const int a_t = act_in[blk*S + t];     // wave-uniform
        float bp = Tb_b[a_t];
        #pragma unroll
        for (int k = 0; k < 9; ++k)
            bp += b_lds[(y + k/3)*PW + x + (k%3)] * Tb_w[a_t*9 + k];

        const float bn = bp * zo_lds[t*NPIX + tid];

        // fused 6-way reduction: sums[0..4] = sum q[a]*bn, sums[5] = sum bn
        float v6[6];
        v6[5] = bn;
        #pragma unroll
        for (int a = 0; a < NA; ++a) v6[a] = q[a] * bn;
        #pragma unroll
        for (int k = 0; k < 6; ++k) {
            float vv = v6[k];
            for (int off = 32; off > 0; off >>= 1) vv += __shfl_down(vv, off);
            v6[k] = vv;
        }
        if (lane == 0) {
            #pragma unroll
            for (int k = 0; k < 6; ++k) partials[wvid][k] = v6[k];
        }
        __syncthreads();
        if (tid < 6) {
            float s = 0.f;
            for (int w2 = 0; w2 < 16; ++w2) s += partials[w2][tid];
            sums[tid] = s;
        }
        __syncthreads();

        const float inv = 1.f / (sums[5] + EPSV);
        if (tid < NA) {
            float oj = FL_b[tid];
            #pragma unroll
            for (int a = 0; a < NA; ++a) oj += (sums[a] * inv) * FL_w[tid*NA + a];
            out[(t*B + blk)*NA + tid] = oj;
        }
        b_lds[pidx] = bn * inv;   // normalized belief for next step
        __syncthreads();
    }

    // ---- final belief output ----
    out[S*B*NA + blk*NPIX + tid] = b_lds[pidx];
}

extern "C" void kernel_launch(void* const* d_in, const int* in_sizes, int n_in,
                              void* d_out, int out_size, void* d_ws, size_t ws_size,
                              hipStream_t stream)
{
    const float* map_in = (const float*)d_in[0];
    const float* b0     = (const float*)d_in[1];
    const int*   act_in = (const int*)  d_in[2];
    const float* obs_in = (const float*)d_in[3];
    // d_in[4] = is_start (unused: reference uses b0 either way)
    const int*   step_p = (const int*)  d_in[5];
    const int*   vik_p  = (const int*)  d_in[6];
    const float* Tb_w = (const float*)d_in[7];
    const float* Tb_b = (const float*)d_in[8];
    const float* Tv_w = (const float*)d_in[9];
    const float* Tv_b = (const float*)d_in[10];
    const float* Z1_w = (const float*)d_in[11];
    const float* Z1_b = (const float*)d_in[12];
    const float* Z2_w = (const float*)d_in[13];
    const float* Z2_b = (const float*)d_in[14];
    const float* O1_w = (const float*)d_in[15];
    const float* O1_b = (const float*)d_in[16];
    const float* O3_w = (const float*)d_in[17];
    const float* O3_b = (const float*)d_in[18];
    const float* R1_w = (const float*)d_in[19];
    const float* R1_b = (const float*)d_in[20];
    const float* R2_w = (const float*)d_in[21];
    const float* R2_b = (const float*)d_in[22];
    const float* FL_w = (const float*)d_in[23];
    const float* FL_b = (const float*)d_in[24];

    const int B = in_sizes[1] / NPIX;   // b0 is (B,32,32)

    hipLaunchKernelGGL(vin_fused, dim3(B), dim3(1024), 0, stream,
        map_in, b0, act_in, obs_in, step_p, vik_p,
        Tb_w, Tb_b, Tv_w, Tv_b, Z1_w, Z1_b, Z2_w, Z2_b,
        O1_w, O1_b, O3_w, O3_b, R1_w, R1_b, R2_w, R2_b,
        FL_w, FL_b, (float*)d_out, B);
}